// Round 9
// baseline (117.192 us; speedup 1.0000x reference)
//
#include <hip/hip_runtime.h>

#define BATCH 131072
#define NS    300
#define H     100
#define BLK   256
#define EPB   128                 /* elements per block */
#define NBLK  (BATCH / EPB)       /* 1024 blocks */

/* LDS float-offsets (total 51712 B = 12928 floats -> 3 blocks/CU) */
#define H1_STR   101              /* padded row: 101 mod 32 = 5, gcd(5,32)=1 -> conflict-free */
#define PARTF(g) ((g) * 3072)     /* partial head sums: [grp][jc*64+lane][12], aliases h1 rows 0-63 */
#define RAWF     6144             /* raw params: [el][12], aliases h1 rows ~60-76 (dead by then) */

__global__ void w2_transpose(const float* __restrict__ W2, float* __restrict__ W2T) {
    int i = blockIdx.x * 256 + threadIdx.x;
    if (i < H * H) {
        int j = i / H, k = i - j * H;
        W2T[k * H + j] = W2[i];
    }
}

__global__ __launch_bounds__(BLK)
void lorentz_fused(const float* __restrict__ G,   const float* __restrict__ W1,
                   const float* __restrict__ b1,  const float* __restrict__ W2T,
                   const float* __restrict__ b2,  const float* __restrict__ Ww0,
                   const float* __restrict__ Wwp, const float* __restrict__ Wg,
                   float* __restrict__ out)
{
    __shared__ __align__(16) float sF[12928];

    const int tid  = threadIdx.x;
    const int lane = tid & 63;
    const int jc   = __builtin_amdgcn_readfirstlane(tid >> 6);  /* wave id, forced SGPR */
    const int jc25 = jc * 25;

    /* ---- phase 1: h1 -> LDS. thread (el=tid>>1, half=tid&1) computes 50 values. ---- */
    {
        const int el   = tid >> 1;
        const int half = tid & 1;
        const float4* gp = (const float4*)(G + (size_t)(blockIdx.x * EPB + el) * 8);
        const float4 gA = gp[0], gB = gp[1];
        float* h1row = sF + el * H1_STR + half * 50;
        const float* w1p = W1 + (half * 50) * 8;
        const float* b1p = b1 + half * 50;
#pragma unroll 2
        for (int i = 0; i < 50; ++i) {
            const float4 ra = ((const float4*)(w1p + i * 8))[0];
            const float4 rb = ((const float4*)(w1p + i * 8))[1];
            float s0 = fmaf(gA.x, ra.x, b1p[i]);
            float s1 = gA.y * ra.y;
            s0 = fmaf(gA.z, ra.z, s0);  s1 = fmaf(gA.w, ra.w, s1);
            s0 = fmaf(gB.x, rb.x, s0);  s1 = fmaf(gB.y, rb.y, s1);
            s0 = fmaf(gB.z, rb.z, s0);  s1 = fmaf(gB.w, rb.w, s1);
            h1row[i] = fmaxf(s0 + s1, 0.f);
        }
    }
    __syncthreads();

    /* ---- phase 2: wave jc computes h2[jc*25 .. +25) for 64 elements (lane = el).
       W2T row chunks are wave-uniform -> SGPR s_load; h1 streamed from LDS (1 b32/k).
       One v_fmac per MAC, 25 independent acc chains. ---- */
#pragma unroll 1
    for (int grp = 0; grp < 2; ++grp) {
        const int el = grp * 64 + lane;
        const float* h1p = sF + el * H1_STR;

        float acc[25];
#pragma unroll
        for (int u = 0; u < 25; ++u) acc[u] = b2[jc25 + u];

#pragma unroll 2
        for (int k = 0; k < H; ++k) {
            const float h = h1p[k];                     /* ds_read_b32, conflict-free */
            const float* wr = W2T + k * H + jc25;       /* uniform -> s_load */
#pragma unroll
            for (int u = 0; u < 25; ++u) acc[u] = fmaf(wr[u], h, acc[u]);
        }
#pragma unroll
        for (int u = 0; u < 25; ++u) acc[u] = fmaxf(acc[u], 0.f);

        /* all lanes done reading h1 for this grp before aliased partial writes */
        __syncthreads();

        /* heads: 12 partial sums over this wave's 25 j's; write straight to LDS */
        float* part = sF + PARTF(grp) + (jc * 64 + lane) * 12;
#pragma unroll
        for (int t = 0; t < 3; ++t) {
            const float* HB = (t == 0) ? Ww0 : (t == 1) ? Wwp : Wg;
#pragma unroll
            for (int m = 0; m < 4; ++m) {
                const float* hr = HB + m * H + jc25;    /* uniform -> s_load */
                float s = 0.f;
#pragma unroll
                for (int u = 0; u < 25; ++u) s = fmaf(hr[u], acc[u], s);
                part[t * 4 + m] = s;
            }
        }
    }
    __syncthreads();

    /* ---- combine partials across the 4 jc-waves; relu; raw[el][12] ---- */
    for (int s = tid; s < EPB * 12; s += BLK) {         /* 6 iterations */
        const int el = s / 12, p = s - el * 12;
        const int base = PARTF(el >> 6) + (el & 63) * 12 + p;
        float v = sF[base] + sF[base + 64 * 12] + sF[base + 128 * 12] + sF[base + 192 * 12];
        sF[RAWF + s] = fmaxf(v, 0.f);
    }
    __syncthreads();

    /* ---- phase 3: spectrum, owner-computes. thread pair (el=tid>>1, half=tid&1)
       writes element el's row; params in registers; no LDS reads in the loop. ---- */
    {
        const int el   = tid >> 1;
        const int half = tid & 1;
        const float4* rawq = (const float4*)(sF + RAWF) + el * 3;
        const float4 w0v = rawq[0], wpv = rawq[1], ggv = rawq[2];

        const float4 P0 = make_float4(w0v.x * w0v.x, w0v.y * w0v.y, w0v.z * w0v.z, w0v.w * w0v.w);
        const float4 P1 = make_float4(ggv.x * ggv.x, ggv.y * ggv.y, ggv.z * ggv.z, ggv.w * ggv.w);
        const float4 P2 = make_float4(wpv.x * wpv.x * ggv.x, wpv.y * wpv.y * ggv.y,
                                      wpv.z * wpv.z * ggv.z, wpv.w * wpv.w * ggv.w);

        float4* out4 = (float4*)out + (size_t)(blockIdx.x * EPB + el) * (NS / 4);
        for (int k4 = half; k4 < NS / 4; k4 += 2) {     /* 38/37 iters; pair covers the row */
            const float kb = (float)(k4 << 2);
            float4 r; float* rp = (float*)&r;
#pragma unroll
            for (int i = 0; i < 4; ++i) {
                const float w   = 0.5f + (kb + (float)i) * 0.015f;
                const float wsq = w * w;
                const float t0 = P0.x - wsq, t1 = P0.y - wsq,
                            t2 = P0.z - wsq, t3 = P0.w - wsq;
                const float d0 = fmaf(t0, t0, wsq * P1.x);
                const float d1 = fmaf(t1, t1, wsq * P1.y);
                const float d2 = fmaf(t2, t2, wsq * P1.z);
                const float d3 = fmaf(t3, t3, wsq * P1.w);
                const float d01 = d0 * d1, d23 = d2 * d3;
                const float D   = d01 * d23;
                const float n01 = fmaf(P2.y, d0, P2.x * d1);
                const float n23 = fmaf(P2.w, d2, P2.z * d3);
                const float N   = fmaf(n01, d23, n23 * d01);
                rp[i] = w * (N * __builtin_amdgcn_rcpf(D));
            }
            out4[k4] = r;
        }
    }
}

extern "C" void kernel_launch(void* const* d_in, const int* in_sizes, int n_in,
                              void* d_out, int out_size, void* d_ws, size_t ws_size,
                              hipStream_t stream) {
    const float* G   = (const float*)d_in[0];
    const float* W1  = (const float*)d_in[1];
    const float* b1  = (const float*)d_in[2];
    const float* W2  = (const float*)d_in[3];
    const float* b2  = (const float*)d_in[4];
    const float* Ww0 = (const float*)d_in[5];
    const float* Wwp = (const float*)d_in[6];
    const float* Wg  = (const float*)d_in[7];
    float* out = (float*)d_out;
    float* W2T = (float*)d_ws;                 /* 40000 B of scratch */

    w2_transpose<<<(H * H + 255) / 256, 256, 0, stream>>>(W2, W2T);
    lorentz_fused<<<NBLK, BLK, 0, stream>>>(G, W1, b1, W2T, b2, Ww0, Wwp, Wg, out);
}